// Round 4
// baseline (320.723 us; speedup 1.0000x reference)
//
#include <hip/hip_runtime.h>

#define N_NODES 100000
#define N_EDGES 3200000
#define EMBED_DIM 64
#define BATCH 16384
#define MAX_SLOTS 32768

// Edge slicing / node partitioning for hist+scatter:
#define HP 8            // node partitions (LDS-sized)
#define NPP 12500       // nodes per partition
#define WPP 6250        // packed 2x16-bit words per partition
#define HG 64           // edge slices
#define EPS 50000       // edges per slice
#define I4PS 12500      // int4 loads per slice
#define WP4 12500       // packed words per 25000-node partials partition

// partials layout: [p4 in 0..3][g in 0..63][word in 0..12499] (uint32 = 2x16-bit node counts)
// After k_prefix: partials[p4][g][w] = exclusive prefix over g (per packed half).

// Workspace (byte offsets), peak 26,400,000 B (proven available in round 1):
//   slot     @ 0         : 100000 ints (0 = unused, else slot_id+1)
//   counters @ 400000    : 16 ints ([0]=nSlots, [1]=binTotal)
//   cnt      @ 400064    : 100000 ints (in-degree)
//   cursor   @ 800064    : 100000 ints (bin region START; -1 = not needed)
//   dinv     @ 1200064   : 100000 floats
//   nodelist @ 1600064   : 32768 ints
//   partials @ 1731136   : 4*64*12500 words = 12,800,000 B (dead after scatter)
//   emb      @ 1731136   : OVERLAYS partials (8.4 MB, written by gather)
//   bins     @ 14531136  : ~2.96M int capacity (expected fill 0.896M)
#define OFF_SLOT     0
#define OFF_COUNTERS 400000
#define OFF_CNT      400064
#define OFF_CURSOR   800064
#define OFF_DINV     1200064
#define OFF_NODELIST 1600064
#define OFF_PARTIALS 1731136
#define OFF_EMB      1731136
#define OFF_BINS     14531136

__global__ void k_init(int4* slot4, int* counters) {
    int i = blockIdx.x * blockDim.x + threadIdx.x;
    int stride = gridDim.x * blockDim.x;
    for (int j = i; j < 25000; j += stride) slot4[j] = make_int4(0, 0, 0, 0);
    if (i < 16) counters[i] = 0;
}

__global__ void k_flags(const int* __restrict__ pairs, int* __restrict__ slot) {
    int i = blockIdx.x * blockDim.x + threadIdx.x;
    if (i < 2 * BATCH) slot[pairs[i]] = 1;
}

// Wave-aggregated compaction: one atomic per wave.
__global__ void k_compact(int* __restrict__ slot, int* __restrict__ nodelist,
                          int* __restrict__ counters) {
    int n = blockIdx.x * blockDim.x + threadIdx.x;
    int lane = threadIdx.x & 63;
    int want = (n < N_NODES && slot[n]) ? 1 : 0;
    int incl = want;
#pragma unroll
    for (int d = 1; d < 64; d <<= 1) {
        int t = __shfl_up(incl, d, 64);
        if (lane >= d) incl += t;
    }
    int total = __shfl(incl, 63, 64);
    int base = 0;
    if (lane == 63 && total > 0) base = atomicAdd(&counters[0], total);
    base = __shfl(base, 63, 64);
    if (want) {
        int s = base + incl - 1;
        slot[n] = s + 1;
        nodelist[s] = n;
    }
}

__device__ __forceinline__ void hist1(int d, int base, unsigned* h) {
    int t = d - base;
    if ((unsigned)t < (unsigned)NPP) atomicAdd(&h[t >> 1], 1u << ((t & 1) << 4));
}

// Packed 16-bit LDS degree histogram: 512 blocks, 25 KB LDS, zero device atomics.
__global__ void k_hist(const int* __restrict__ dst, unsigned* __restrict__ partials) {
    __shared__ unsigned h[WPP];
    int ps = blockIdx.x & 7, g = blockIdx.x >> 3;
    int base = ps * NPP;
    for (int i = threadIdx.x; i < WPP; i += 256) h[i] = 0;
    __syncthreads();
    const int4* d4 = (const int4*)(dst + g * EPS);
    for (int b0 = 0; b0 < 12288; b0 += 1024) {
        int4 a = d4[b0 + threadIdx.x];
        int4 b = d4[b0 + 256 + threadIdx.x];
        int4 c = d4[b0 + 512 + threadIdx.x];
        int4 e = d4[b0 + 768 + threadIdx.x];
        hist1(a.x, base, h); hist1(a.y, base, h); hist1(a.z, base, h); hist1(a.w, base, h);
        hist1(b.x, base, h); hist1(b.y, base, h); hist1(b.z, base, h); hist1(b.w, base, h);
        hist1(c.x, base, h); hist1(c.y, base, h); hist1(c.z, base, h); hist1(c.w, base, h);
        hist1(e.x, base, h); hist1(e.y, base, h); hist1(e.z, base, h); hist1(e.w, base, h);
    }
    {
        int i = 12288 + threadIdx.x;
        if (i < I4PS) {
            int4 a = d4[i];
            hist1(a.x, base, h); hist1(a.y, base, h); hist1(a.z, base, h); hist1(a.w, base, h);
        }
    }
    __syncthreads();
    unsigned* out = partials + (unsigned)((ps >> 1) * HG + g) * WP4 + (ps & 1) * WPP;
    for (int i = threadIdx.x; i < WPP; i += 256) out[i] = h[i];
}

// In-place exclusive prefix over slices per (node); emits total degree -> cnt.
// Packed halves accumulate independently (per-node degree << 64K: no cross-carry).
__global__ void k_prefix(unsigned* __restrict__ partials, int* __restrict__ cnt) {
    int id = blockIdx.x * blockDim.x + threadIdx.x;
    if (id >= 4 * WP4) return;
    int p4 = id / WP4, w = id - p4 * WP4;
    unsigned base = (unsigned)(p4 * HG) * WP4 + w;
    unsigned run = 0;
#pragma unroll 8
    for (int g = 0; g < HG; ++g) {
        unsigned idx = base + (unsigned)g * WP4;
        unsigned v = partials[idx];
        partials[idx] = run;
        run += v;
    }
    int n0 = p4 * 25000 + 2 * w;
    cnt[n0] = (int)(run & 0xFFFFu);
    cnt[n0 + 1] = (int)(run >> 16);
}

// dinv + wave-aggregated bin-space allocation. cursor = start (-1 if not needed).
__global__ void k_alloc(const int* __restrict__ cnt, const int* __restrict__ slot,
                        float* __restrict__ dinv, int* __restrict__ cursor,
                        int* __restrict__ counters) {
    int n = blockIdx.x * blockDim.x + threadIdx.x;
    int lane = threadIdx.x & 63;
    bool valid = (n < N_NODES);
    int c = 0; bool need = false;
    if (valid) {
        c = cnt[n];
        dinv[n] = rsqrtf((float)c + 1.0f);
        need = (slot[n] != 0);
    }
    int want = need ? c : 0;
    int incl = want;
#pragma unroll
    for (int d = 1; d < 64; d <<= 1) {
        int t = __shfl_up(incl, d, 64);
        if (lane >= d) incl += t;
    }
    int total = __shfl(incl, 63, 64);
    int base = 0;
    if (lane == 63 && total > 0) base = atomicAdd(&counters[1], total);
    base = __shfl(base, 63, 64);
    if (valid) cursor[n] = need ? (base + incl - want) : -1;
}

__device__ __forceinline__ void scat1(int d, int s, int base, unsigned* lc,
                                      const unsigned* __restrict__ pfx,
                                      const int* __restrict__ cursor,
                                      int* __restrict__ bins) {
    int t = d - base;
    if ((unsigned)t < (unsigned)NPP) {
        int cur = cursor[d];
        if (cur >= 0) {
            unsigned sh = (unsigned)(t & 1) << 4;
            unsigned loc = (atomicAdd(&lc[t >> 1], 1u << sh) >> sh) & 0xFFFFu;
            unsigned pre = (pfx[t >> 1] >> sh) & 0xFFFFu;
            bins[cur + (int)(pre + loc)] = s;
        }
    }
}

// Deterministic-position scatter: zero device atomics. 512 blocks, 25 KB LDS.
__global__ void k_scatter(const int* __restrict__ src, const int* __restrict__ dst,
                          const unsigned* __restrict__ partials,
                          const int* __restrict__ cursor, int* __restrict__ bins) {
    __shared__ unsigned lc[WPP];
    int ps = blockIdx.x & 7, g = blockIdx.x >> 3;
    int base = ps * NPP;
    for (int i = threadIdx.x; i < WPP; i += 256) lc[i] = 0;
    __syncthreads();
    const unsigned* pfx = partials + (unsigned)((ps >> 1) * HG + g) * WP4 + (ps & 1) * WPP;
    const int4* d4 = (const int4*)(dst + g * EPS);
    const int4* s4 = (const int4*)(src + g * EPS);
    for (int b0 = 0; b0 < 12288; b0 += 512) {
        int4 da = d4[b0 + threadIdx.x];
        int4 sa = s4[b0 + threadIdx.x];
        int4 db = d4[b0 + 256 + threadIdx.x];
        int4 sb = s4[b0 + 256 + threadIdx.x];
        scat1(da.x, sa.x, base, lc, pfx, cursor, bins);
        scat1(da.y, sa.y, base, lc, pfx, cursor, bins);
        scat1(da.z, sa.z, base, lc, pfx, cursor, bins);
        scat1(da.w, sa.w, base, lc, pfx, cursor, bins);
        scat1(db.x, sb.x, base, lc, pfx, cursor, bins);
        scat1(db.y, sb.y, base, lc, pfx, cursor, bins);
        scat1(db.z, sb.z, base, lc, pfx, cursor, bins);
        scat1(db.w, sb.w, base, lc, pfx, cursor, bins);
    }
    {
        int i = 12288 + threadIdx.x;
        if (i < I4PS) {
            int4 da = d4[i];
            int4 sa = s4[i];
            scat1(da.x, sa.x, base, lc, pfx, cursor, bins);
            scat1(da.y, sa.y, base, lc, pfx, cursor, bins);
            scat1(da.z, sa.z, base, lc, pfx, cursor, bins);
            scat1(da.w, sa.w, base, lc, pfx, cursor, bins);
        }
    }
}

// One wave per needed node. lane = dim. Register accumulation.
__global__ void k_gather(const int* __restrict__ nodelist, const int* __restrict__ cnt,
                         const int* __restrict__ cursor, const int* __restrict__ bins,
                         const float* __restrict__ w, const float* __restrict__ dinv,
                         const float* __restrict__ bias, const int* __restrict__ counters,
                         float* __restrict__ emb) {
    int s = (blockIdx.x * blockDim.x + threadIdx.x) >> 6;
    int lane = threadIdx.x & 63;
    if (s >= counters[0]) return;
    int n = nodelist[s];
    int c = cnt[n];
    int beg = cursor[n];      // start (scatter no longer advances it)
    int end = beg + c;
    float acc = 0.f;
    int j = beg;
    for (; j + 4 <= end; j += 4) {
        int s0 = bins[j], s1 = bins[j + 1], s2 = bins[j + 2], s3 = bins[j + 3];
        float d0 = dinv[s0], d1 = dinv[s1], d2 = dinv[s2], d3 = dinv[s3];
        acc += w[(s0 << 6) + lane] * d0;
        acc += w[(s1 << 6) + lane] * d1;
        acc += w[(s2 << 6) + lane] * d2;
        acc += w[(s3 << 6) + lane] * d3;
    }
    for (; j < end; ++j) {
        int si = bins[j];
        acc += w[(si << 6) + lane] * dinv[si];
    }
    float dn = dinv[n];
    emb[(s << 6) + lane] = acc * dn + w[(n << 6) + lane] * (dn * dn) + bias[lane];
}

// One wave per pair: FM pairwise term == dot(emb_a, emb_b).
__global__ void k_final(const int* __restrict__ pairs, const int* __restrict__ slot,
                        const float* __restrict__ emb, const float* __restrict__ lw,
                        const float* __restrict__ lb, float* __restrict__ out) {
    int p = (blockIdx.x * blockDim.x + threadIdx.x) >> 6;
    int lane = threadIdx.x & 63;
    if (p >= BATCH) return;
    int a = pairs[p * 2 + 0];
    int b = pairs[p * 2 + 1];
    int sa = slot[a] - 1;
    int sb = slot[b] - 1;
    float ea = emb[(sa << 6) + lane];
    float eb = emb[(sb << 6) + lane];
    float prod = ea * eb;
#pragma unroll
    for (int m = 32; m >= 1; m >>= 1) prod += __shfl_xor(prod, m, 64);
    if (lane == 0) out[p] = lw[a] + lw[b] + lb[0] + prod;
}

extern "C" void kernel_launch(void* const* d_in, const int* in_sizes, int n_in,
                              void* d_out, int out_size, void* d_ws, size_t ws_size,
                              hipStream_t stream) {
    const float* gcn_weight    = (const float*)d_in[0];
    const float* gcn_bias      = (const float*)d_in[1];
    const float* linear_weight = (const float*)d_in[2];
    const float* linear_bias   = (const float*)d_in[3];
    const int*   edge_index    = (const int*)d_in[4];
    const int*   pairs         = (const int*)d_in[5];
    float* out = (float*)d_out;

    char* ws = (char*)d_ws;
    int*      slot     = (int*)     (ws + OFF_SLOT);
    int*      counters = (int*)     (ws + OFF_COUNTERS);
    int*      cnt      = (int*)     (ws + OFF_CNT);
    int*      cursor   = (int*)     (ws + OFF_CURSOR);
    float*    dinv     = (float*)   (ws + OFF_DINV);
    int*      nodelist = (int*)     (ws + OFF_NODELIST);
    unsigned* partials = (unsigned*)(ws + OFF_PARTIALS);
    float*    emb      = (float*)   (ws + OFF_EMB);
    int*      bins     = (int*)     (ws + OFF_BINS);

    const int* src_arr = edge_index;
    const int* dst_arr = edge_index + N_EDGES;

    k_init<<<98, 256, 0, stream>>>((int4*)(ws + OFF_SLOT), counters);
    k_flags<<<128, 256, 0, stream>>>(pairs, slot);
    k_compact<<<391, 256, 0, stream>>>(slot, nodelist, counters);
    k_hist<<<HP * HG, 256, 0, stream>>>(dst_arr, partials);
    k_prefix<<<196, 256, 0, stream>>>(partials, cnt);
    k_alloc<<<391, 256, 0, stream>>>(cnt, slot, dinv, cursor, counters);
    k_scatter<<<HP * HG, 256, 0, stream>>>(src_arr, dst_arr, partials, cursor, bins);
    k_gather<<<MAX_SLOTS / 4, 256, 0, stream>>>(nodelist, cnt, cursor, bins, gcn_weight,
                                                dinv, gcn_bias, counters, emb);
    k_final<<<BATCH / 4, 256, 0, stream>>>(pairs, slot, emb, linear_weight, linear_bias, out);
}